// Round 2
// 1114.157 us; speedup vs baseline: 1.0571x; 1.0571x over previous
//
#include <hip/hip_runtime.h>
#include <hip/hip_fp16.h>
#include <cstdint>
#include <cstddef>

#define B_N 65536
#define H_N 1024
#define S_N 1024
#define D_N 128

typedef __attribute__((ext_vector_type(8))) short bf16x8;
typedef __attribute__((ext_vector_type(8))) _Float16 f16x8;
typedef __attribute__((ext_vector_type(4))) float f32x4;

#define MFMA_BF(a, b, c) __builtin_amdgcn_mfma_f32_16x16x32_bf16((a), (b), (c), 0, 0, 0)
#define MFMA_F16(a, b, c) __builtin_amdgcn_mfma_f32_16x16x32_f16((a), (b), (c), 0, 0, 0)

__device__ __forceinline__ unsigned short f2bf(float f) {
    unsigned u = __float_as_uint(f);
    u += 0x7FFFu + ((u >> 16) & 1u);   // RNE
    return (unsigned short)(u >> 16);
}
__device__ __forceinline__ float h2f(unsigned short h) {
    return __half2float(__ushort_as_half(h));
}
__device__ __forceinline__ unsigned short f2h(float f) {
    return __half_as_ushort(__float2half_rn(f));
}
// async global->LDS, 16B/lane. LDS dest = wave-uniform base + lane*16.
__device__ __forceinline__ void async16(void* lds, const void* g) {
    __builtin_amdgcn_global_load_lds(
        (const __attribute__((address_space(1))) unsigned int*)g,
        (__attribute__((address_space(3))) unsigned int*)lds, 16, 0, 0);
}

// ---------------- zero accumulators (csum 1024 + wsum 1024 contiguous) ----------------
__global__ void k_zero(float* p, int n) {
    int i = blockIdx.x * blockDim.x + threadIdx.x;
    if (i < n) p[i] = 0.f;
}

// ---------------- query fp32 -> bf16, row-major ----------------
__global__ __launch_bounds__(256) void k_prep_q(const float* __restrict__ q,
                                                unsigned short* __restrict__ qb) {
    size_t i = ((size_t)blockIdx.x * 256 + threadIdx.x) * 8;
    float4 a = *(const float4*)(q + i);
    float4 b = *(const float4*)(q + i + 4);
    uint4 o;
    o.x = (unsigned)f2bf(a.x) | ((unsigned)f2bf(a.y) << 16);
    o.y = (unsigned)f2bf(a.z) | ((unsigned)f2bf(a.w) << 16);
    o.z = (unsigned)f2bf(b.x) | ((unsigned)f2bf(b.y) << 16);
    o.w = (unsigned)f2bf(b.z) | ((unsigned)f2bf(b.w) << 16);
    *(uint4*)(qb + i) = o;
}

// ---------------- W transpose+convert: wcat[n][k] bf16, n in [0,2048) ----------------
__global__ __launch_bounds__(256) void k_prep_w(const float* __restrict__ Wr,
                                                const float* __restrict__ Ww,
                                                unsigned short* __restrict__ wcat) {
    __shared__ float t[32][33];
    const int kb = blockIdx.x * 32, nb = blockIdx.y * 32;
    const float* src = blockIdx.z ? Ww : Wr;
    const int tx = threadIdx.x & 31, ty = threadIdx.x >> 5;
#pragma unroll
    for (int i = 0; i < 4; i++) {
        int r = ty + i * 8;
        t[r][tx] = src[(size_t)(kb + r) * S_N + nb + tx];
    }
    __syncthreads();
    unsigned short* dst = wcat + (size_t)blockIdx.z * 1024 * 1024;
#pragma unroll
    for (int i = 0; i < 4; i++) {
        int r = ty + i * 8;
        dst[(size_t)(nb + r) * 1024 + kb + tx] = f2bf(t[tx][r]);
    }
}

// ---------------- memory transpose: memT[d][s] fp16 ----------------
__global__ __launch_bounds__(256) void k_prep_mem(const float* __restrict__ mem,
                                                  unsigned short* __restrict__ memT) {
    __shared__ float t[32][33];
    const int db = blockIdx.x * 32, sb = blockIdx.y * 32;
    const int tx = threadIdx.x & 31, ty = threadIdx.x >> 5;
#pragma unroll
    for (int i = 0; i < 4; i++) {
        int r = ty + i * 8;
        t[r][tx] = mem[(size_t)(sb + r) * D_N + db + tx];
    }
    __syncthreads();
#pragma unroll
    for (int i = 0; i < 4; i++) {
        int r = ty + i * 8;
        memT[(size_t)(db + r) * 1024 + sb + tx] = f2h(t[tx][r]);
    }
}

// ---------------- content column-sum over B ----------------
__global__ __launch_bounds__(256) void k_content(const float* __restrict__ content,
                                                 float* __restrict__ csum) {
    const int tid = threadIdx.x;
    const size_t r0 = (size_t)blockIdx.x * 128;
    float4 a = {0.f, 0.f, 0.f, 0.f};
    const float* base = content + r0 * H_N + tid * 4;
#pragma unroll 8
    for (int r = 0; r < 128; r++) {
        float4 v = *(const float4*)(base + (size_t)r * H_N);
        a.x += v.x; a.y += v.y; a.z += v.z; a.w += v.w;
    }
    atomicAdd(&csum[tid * 4 + 0], a.x);
    atomicAdd(&csum[tid * 4 + 1], a.y);
    atomicAdd(&csum[tid * 4 + 2], a.z);
    atomicAdd(&csum[tid * 4 + 3], a.w);
}

// =====================================================================================
// main GEMM: logits[rows][2048] = exp(Q @ [Wr|Ww]^T + bias) fp16
// 256x256 tile, BK=64, 8 waves (2M x 4N), 8-phase counted-vmcnt schedule (T1-T5).
// LDS 128 KiB: buf d in {0,1}: A at d*65536, B at d*65536+32768; 256 rows x 128B each.
// Swizzle: phys = logical ^ ((row&7)<<4)  (involution; 16B-chunk preserving).
//
// Half-tile liveness (halves are SPATIAL row ranges, read in BOTH quadrant phases):
//   buf0.B (rows 0-127 / 128-255): read ph1+ph2  -> restage ph3/ph4
//   buf0.A:                        read ph1+ph3  -> restage ph5/ph6
//   buf1.B:                        read ph5+ph6  -> restage ph7/ph8
//   buf1.A:                        read ph5+ph7  -> restage next ph1/ph2
// vmcnt(4) at ph4 (buf1 resident before ph5) and ph8 (buf0 resident before ph1').
// =====================================================================================
#define BARX() asm volatile("s_barrier" ::: "memory")
#define LGK0() asm volatile("s_waitcnt lgkmcnt(0)" ::: "memory")
#define VMC4() asm volatile("s_waitcnt vmcnt(4)" ::: "memory")

__device__ __forceinline__ bf16x8 ldfrag(const char* buf, int row, int ko) {
    int off = (row * 128 + ko) ^ ((row & 7) << 4);
    return *(const bf16x8*)(buf + off);
}
__device__ __forceinline__ void rd_a(const char* bufA, int wm, int l16, int g, int mh,
                                     bf16x8 a[4][2]) {
#pragma unroll
    for (int m2 = 0; m2 < 4; m2++) {
        int row = wm * 128 + (mh * 4 + m2) * 16 + l16;
#pragma unroll
        for (int ks = 0; ks < 2; ks++) a[m2][ks] = ldfrag(bufA, row, ks * 64 + g * 16);
    }
}
__device__ __forceinline__ void rd_b(const char* bufB, int wn, int l16, int g, int nh,
                                     bf16x8 b[2][2]) {
#pragma unroll
    for (int n2 = 0; n2 < 2; n2++) {
        int row = wn * 64 + (nh * 2 + n2) * 16 + l16;
#pragma unroll
        for (int ks = 0; ks < 2; ks++) b[n2][ks] = ldfrag(bufB, row, ks * 64 + g * 16);
    }
}
__device__ __forceinline__ void mm16(f32x4 acc[8][4], bf16x8 a[4][2], bf16x8 b[2][2],
                                     int mh, int nh) {
    __builtin_amdgcn_s_setprio(1);
#pragma unroll
    for (int m2 = 0; m2 < 4; m2++)
#pragma unroll
        for (int n2 = 0; n2 < 2; n2++) {
            f32x4 c = acc[mh * 4 + m2][nh * 2 + n2];
            c = MFMA_BF(a[m2][0], b[n2][0], c);
            c = MFMA_BF(a[m2][1], b[n2][1], c);
            acc[mh * 4 + m2][nh * 2 + n2] = c;
        }
    __builtin_amdgcn_s_setprio(0);
}

__global__ __launch_bounds__(512, 2) void k_gemm(const unsigned short* __restrict__ qb,
                                                 const unsigned short* __restrict__ wcat,
                                                 const float* __restrict__ b_read,
                                                 const float* __restrict__ b_write,
                                                 unsigned short* __restrict__ logits) {
    __shared__ __align__(16) char sm[131072];
    const int tid = threadIdx.x;
    const int w = tid >> 6, lane = tid & 63;
    const int wm = w >> 2, wn = w & 3;
    const int l16 = lane & 15, g = lane >> 4;

    // T1: bijective chunked XCD swizzle (nwg % 8 == 0 since CB % 256 == 0)
    const int nwg = (int)gridDim.y * 8;
    const int lin = (int)blockIdx.y * 8 + (int)blockIdx.x;
    const int nlin = (lin & 7) * (nwg >> 3) + (lin >> 3);
    const int by = nlin >> 3, bx = nlin & 7;
    const size_t mrow = (size_t)by * 256;

    // staging chunk -> (row, kbyte) with inverse swizzle baked into the GLOBAL source
    int g0[2];
#pragma unroll
    for (int j = 0; j < 2; j++) {
        int c = w * 64 + j * 512 + lane;                 // chunk within half-tile
        int lc = (c * 16) ^ (((c >> 3) & 7) << 4);       // logical byte (involution)
        g0[j] = (lc >> 7) * 2048 + (lc & 127);           // row*2048B + kbyte
    }
    const char* aB = (const char*)qb + mrow * 2048;
    const char* wB = (const char*)wcat + (size_t)bx * 256 * 2048;
    char* smW = (char*)sm + w * 1024;

#define STG(d, opb, h, ktB) do {                                              \
        const char* s_ = ((opb) ? wB : aB) + ((h) * 262144 + (ktB));          \
        char* d_ = smW + ((d) * 65536 + (opb) * 32768 + (h) * 16384);         \
        async16(d_,        s_ + g0[0]);                                       \
        async16(d_ + 8192, s_ + g0[1]);                                       \
    } while (0)

    f32x4 acc[8][4];
#pragma unroll
    for (int m = 0; m < 8; m++)
#pragma unroll
        for (int n = 0; n < 4; n++) acc[m][n] = (f32x4){0.f, 0.f, 0.f, 0.f};

    const char* bufA0 = (const char*)sm;
    const char* bufB0 = (const char*)sm + 32768;
    const char* bufA1 = (const char*)sm + 65536;
    const char* bufB1 = (const char*)sm + 98304;
    bf16x8 a[4][2], b0[2][2], b1[2][2];

    // prologue: t0 full (8 loads) + t1.B0/B1 (4 loads); vmcnt(4) drains exactly t0
    STG(0, 0, 0, 0); STG(0, 1, 0, 0); STG(0, 0, 1, 0); STG(0, 1, 1, 0);
    STG(1, 1, 0, 128); STG(1, 1, 1, 128);
    VMC4(); BARX();

#pragma unroll 1
    for (int i = 0; i < 8; i++) {
        const int kA = (2 * i + 1) * 128;                   // A-halves of tile 2i+1 (<=15)
        int t2 = 2 * i + 2; if (t2 > 15) t2 = 15;           // clamp dead prefetch
        int t3 = 2 * i + 3; if (t3 > 15) t3 = 15;
        const int kB = t2 * 128, kC = t3 * 128;

        // ---- tile 2i from buf0 ----
        // ph1 (mh0,nh0): stage t(2i+1).A0 -> buf1.A0 (last read prev ph7)
        rd_a(bufA0, wm, l16, g, 0, a); rd_b(bufB0, wn, l16, g, 0, b0);
        STG(1, 0, 0, kA);
        BARX(); LGK0(); mm16(acc, a, b0, 0, 0); BARX();
        // ph2 (mh0,nh1): stage t(2i+1).A1 -> buf1.A1 (last read prev ph7)
        rd_b(bufB0, wn, l16, g, 1, b1);
        STG(1, 0, 1, kA);
        BARX(); LGK0(); mm16(acc, a, b1, 0, 1); BARX();
        // ph3 (mh1,nh1): stage t(2i+2).B0 -> buf0.B0 (last read ph2)
        rd_a(bufA0, wm, l16, g, 1, a);
        STG(0, 1, 0, kB);
        BARX(); LGK0(); mm16(acc, a, b1, 1, 1); BARX();
        // ph4 (mh1,nh0): stage t(2i+2).B1 -> buf0.B1; drain: buf1 fully resident
        STG(0, 1, 1, kB);
        VMC4(); BARX(); mm16(acc, a, b0, 1, 0); BARX();

        // ---- tile 2i+1 from buf1 ----
        // ph5: stage t(2i+2).A0 -> buf0.A0 (last read ph3)
        rd_a(bufA1, wm, l16, g, 0, a); rd_b(bufB1, wn, l16, g, 0, b0);
        STG(0, 0, 0, kB);
        BARX(); LGK0(); mm16(acc, a, b0, 0, 0); BARX();
        // ph6: stage t(2i+2).A1 -> buf0.A1 (last read ph3)
        rd_b(bufB1, wn, l16, g, 1, b1);
        STG(0, 0, 1, kB);
        BARX(); LGK0(); mm16(acc, a, b1, 0, 1); BARX();
        // ph7: stage t(2i+3).B0 -> buf1.B0 (last read ph6)
        rd_a(bufA1, wm, l16, g, 1, a);
        STG(1, 1, 0, kC);
        BARX(); LGK0(); mm16(acc, a, b1, 1, 1); BARX();
        // ph8: stage t(2i+3).B1 -> buf1.B1; drain: buf0 fully resident
        STG(1, 1, 1, kC);
        VMC4(); BARX(); mm16(acc, a, b0, 1, 0); BARX();
    }
#undef STG

    // epilogue: exp + bias, fp16 store (cols of this block all in one half)
    const float* bias = (bx < 4) ? (b_read + bx * 256) : (b_write + bx * 256 - 1024);
#pragma unroll
    for (int nt = 0; nt < 4; nt++) {
        const int col = wn * 64 + nt * 16 + l16;
        const float bv = bias[col];
#pragma unroll
        for (int mt = 0; mt < 8; mt++) {
            const int row0 = wm * 128 + mt * 16 + g * 4;
#pragma unroll
            for (int r = 0; r < 4; r++) {
                float e = __expf(acc[mt][nt][r] + bv);      // |logit|<~5 -> no max needed
                logits[(mrow + row0 + r) * 2048 + (size_t)bx * 256 + col] = f2h(e);
            }
        }
    }
}

// ---------------- fused post: row-sums + PV (f16 MFMA) + write-col partials ----------------
// 16 rows/block, 256 thr (4 waves). LDS 66 KB -> 2 blocks/CU.
__global__ __launch_bounds__(256) void k_post(const unsigned short* __restrict__ logits,
                                              const unsigned short* __restrict__ memT,
                                              float* __restrict__ out,
                                              float* __restrict__ wpart, int blk0) {
    __shared__ unsigned short L[16 * 2056];   // row pad +8
    __shared__ float sInvR[16], sInvW[16];
    const int tid = threadIdx.x;
    const size_t r0 = (size_t)blockIdx.x * 16;
#pragma unroll
    for (int i = 0; i < 16; i++) {
        int c2 = i * 256 + tid;
        int r = c2 >> 8, off = (c2 & 255) * 8;
        *(uint4*)&L[r * 2056 + off] = *(const uint4*)&logits[(r0 + r) * 2048 + off];
    }
    __syncthreads();
    {
        const int r = tid >> 4, sub = tid & 15;
        const unsigned* row = (const unsigned*)&L[r * 2056];
        float zr = 0.f, zw = 0.f;
#pragma unroll 8
        for (int i = 0; i < 32; i++) {
            unsigned u = row[i * 16 + sub];
            zr += h2f((unsigned short)(u & 0xffff)) + h2f((unsigned short)(u >> 16));
            unsigned v = row[512 + i * 16 + sub];
            zw += h2f((unsigned short)(v & 0xffff)) + h2f((unsigned short)(v >> 16));
        }
        zr += __shfl_xor(zr, 1); zr += __shfl_xor(zr, 2);
        zr += __shfl_xor(zr, 4); zr += __shfl_xor(zr, 8);
        zw += __shfl_xor(zw, 1); zw += __shfl_xor(zw, 2);
        zw += __shfl_xor(zw, 4); zw += __shfl_xor(zw, 8);
        if (sub == 0) { sInvR[r] = 1.f / zr; sInvW[r] = 1.f / zw; }
    }
    __syncthreads();
    // PV: out[16 x 128] = (e_read @ memT^T) * invZ ; wave w covers cols w*32..+31
    const int wave = tid >> 6, lane = tid & 63;
    const int l16 = lane & 15, g = lane >> 4;
    f32x4 acc0 = (f32x4){0.f, 0.f, 0.f, 0.f}, acc1 = acc0;
    for (int k0 = 0; k0 < 1024; k0 += 32) {
        f16x8 a  = *(const f16x8*)&L[l16 * 2056 + k0 + g * 8];
        f16x8 b0 = *(const f16x8*)&memT[(size_t)(wave * 32 + l16) * 1024 + k0 + g * 8];
        f16x8 b1 = *(const f16x8*)&memT[(size_t)(wave * 32 + 16 + l16) * 1024 + k0 + g * 8];
        acc0 = MFMA_F16(a, b0, acc0);
        acc1 = MFMA_F16(a, b1, acc1);
    }
#pragma unroll
    for (int r = 0; r < 4; r++) {
        int row = g * 4 + r;
        float iz = sInvR[row];
        out[(r0 + row) * D_N + wave * 32 + l16] = acc0[r] * iz;
        out[(r0 + row) * D_N + wave * 32 + 16 + l16] = acc1[r] * iz;
    }
    // write-half column partial sums (4 cols/thread)
    float c0 = 0.f, c1 = 0.f, c2 = 0.f, c3 = 0.f;
#pragma unroll
    for (int r = 0; r < 16; r++) {
        float iz = sInvW[r];
        uint2 u = *(const uint2*)&L[r * 2056 + 1024 + tid * 4];
        c0 += h2f((unsigned short)(u.x & 0xffff)) * iz;
        c1 += h2f((unsigned short)(u.x >> 16)) * iz;
        c2 += h2f((unsigned short)(u.y & 0xffff)) * iz;
        c3 += h2f((unsigned short)(u.y >> 16)) * iz;
    }
    float4 o = {c0, c1, c2, c3};
    *(float4*)&wpart[(size_t)(blk0 + blockIdx.x) * 1024 + tid * 4] = o;
}

// ---------------- reduce write-col partials: wsum[c] += partial ----------------
__global__ __launch_bounds__(256) void k_wreduce(const float* __restrict__ wpart,
                                                 float* __restrict__ wsum) {
    const int c = (blockIdx.x & 3) * 256 + threadIdx.x;
    const int i0 = (blockIdx.x >> 2) * 512;
    float s0 = 0.f, s1 = 0.f;
    for (int i = 0; i < 512; i += 2) {
        s0 += wpart[(size_t)(i0 + i) * 1024 + c];
        s1 += wpart[(size_t)(i0 + i + 1) * 1024 + c];
    }
    atomicAdd(&wsum[c], s0 + s1);
}

// ---------------- c_mean = (csum/B) @ W_content + b_content ----------------
__global__ void k_cmean(const float* __restrict__ csum, const float* __restrict__ Wc,
                        const float* __restrict__ bc, float* __restrict__ cmean) {
    const int d = blockIdx.x, t = threadIdx.x;
    float s = 0.f;
#pragma unroll
    for (int j = 0; j < 16; j++) {
        int h = j * 64 + t;
        s += csum[h] * Wc[h * D_N + d];
    }
#pragma unroll
    for (int o = 1; o < 64; o <<= 1) s += __shfl_xor(s, o);
    if (t == 0) cmean[d] = s * (1.0f / (float)B_N) + bc[d];
}

// ---------------- memory update + age ----------------
__global__ __launch_bounds__(256) void k_final(const float* __restrict__ memory,
                                               const float* __restrict__ age,
                                               const float* __restrict__ wsum,
                                               const float* __restrict__ cmean,
                                               float* __restrict__ out) {
    const int idx = blockIdx.x * 256 + threadIdx.x;
    const int s = idx >> 7, d = idx & 127;
    const float wm = wsum[s] * (1.0f / (float)B_N);
    const bool mask = wm > 0.01f;
    const float cons = 1.0f / (1.0f + __expf(-0.1f * age[s]));
    const float f = wm * cons;
    const float m = memory[idx];
    const float nm = mask ? ((1.0f - f) * m + f * cmean[d]) : m;
    out[(size_t)B_N * D_N + idx] = nm;
    if (d == 0) out[(size_t)B_N * D_N + (size_t)S_N * D_N + s] = age[s] + (mask ? 1.0f : 0.0f);
}

extern "C" void kernel_launch(void* const* d_in, const int* in_sizes, int n_in,
                              void* d_out, int out_size, void* d_ws, size_t ws_size,
                              hipStream_t stream) {
    const float* query    = (const float*)d_in[0];
    const float* content  = (const float*)d_in[1];
    const float* memory   = (const float*)d_in[2];
    const float* age      = (const float*)d_in[3];
    const float* W_read   = (const float*)d_in[4];
    const float* b_read   = (const float*)d_in[5];
    const float* W_write  = (const float*)d_in[6];
    const float* b_write  = (const float*)d_in[7];
    const float* W_cont   = (const float*)d_in[8];
    const float* b_cont   = (const float*)d_in[9];

    char* ws = (char*)d_ws;
    unsigned short* wcat   = (unsigned short*)ws;                    // 4 MB bf16 [2048][1024]
    unsigned short* memT   = (unsigned short*)(ws + (4u << 20));     // 256 KB fp16 [128][1024]
    float* csum            = (float*)(ws + 4456448);                 // 4 KB
    float* wsum            = csum + 1024;                            // 4 KB (contiguous)
    float* cmean           = csum + 2048;
    float* wpart           = (float*)(ws + (8u << 20));              // 16 MB [4096][1024]
    char* dynbase          = ws + (24u << 20);
    float* out = (float*)d_out;

    // chunk sizing: per row needs 2 KB (qbf) + 4 KB (logits); 256-row granularity
    long long avail = (long long)ws_size - (24ll << 20);
    long long maxrows = avail > 0 ? avail / 6144 : 0;
    int CB = (int)((maxrows / 256) * 256);
    if (CB > B_N) CB = B_N;
    if (CB < 256) CB = 256;
    unsigned short* qbf    = (unsigned short*)dynbase;
    unsigned short* logits = (unsigned short*)(dynbase + (size_t)CB * 2048);

    k_zero<<<8, 256, 0, stream>>>(csum, 2048);
    k_prep_w<<<dim3(32, 32, 2), 256, 0, stream>>>(W_read, W_write, wcat);
    k_prep_mem<<<dim3(4, 32), 256, 0, stream>>>(memory, memT);
    k_content<<<512, 256, 0, stream>>>(content, csum);

    for (int s0 = 0; s0 < B_N; s0 += CB) {
        int rows = B_N - s0;
        if (rows > CB) rows = CB;
        k_prep_q<<<rows / 2, 256, 0, stream>>>(query + (size_t)s0 * H_N, qbf);
        k_gemm<<<dim3(8, rows / 256), 512, 0, stream>>>(qbf, wcat, b_read, b_write, logits);
        k_post<<<rows / 16, 256, 0, stream>>>(logits, memT, out + (size_t)s0 * D_N,
                                              wpart, s0 / 16);
    }
    k_wreduce<<<32, 256, 0, stream>>>(wpart, wsum);
    k_cmean<<<128, 64, 0, stream>>>(csum, W_cont, b_cont, cmean);
    k_final<<<512, 256, 0, stream>>>(memory, age, wsum, cmean, out);
}